// Round 1
// baseline (6721.415 us; speedup 1.0000x reference)
//
#include <hip/hip_runtime.h>

// ---------------------------------------------------------------------------
// TemporalAttnLayer: B=256, T=64, M=256, H=256
//
// Design:
//  - Persistent cooperative kernel: 256 workgroups x 256 threads (1 wg / CU).
//  - 8 independent groups of 32 wgs; group g owns batch rows [32g, 32g+32).
//    All cross-wg data flow is group-local -> group barriers (not grid-wide).
//  - Phase 1 (per step): weight GEMMs x1=[d,sp]@W_d.T and g1=d@W_hh.T+biases,
//    B-tiled across the group so each weight row is read ~8x/step total
//    (not 256x) -> L2-bound traffic ~46MB/step grid-wide.
//  - Phase 2 (per step, wg w handles b=w): attention tanh-dot over y1[b]
//    (bf16, global scratch, L2-resident), softmax over T in one wave,
//    c from enc[b] in LDS (bf16), scalar y_til, LSTM cell (sp in registers).
//  - y1 = enc @ U_d^T precomputed once per launch (fp32 math, bf16 store).
// ---------------------------------------------------------------------------

#define Bx 256
#define Tx 64
#define Mx 256
#define Hx 256
#define NB 256
#define NT 256

__device__ __forceinline__ float4 ld4(const float* p) { return *(const float4*)p; }
__device__ __forceinline__ float dot4(float4 a, float4 b) {
  return a.x*b.x + a.y*b.y + a.z*b.z + a.w*b.w;
}
__device__ __forceinline__ float bf2f(unsigned short u) {
  union { unsigned int i; float f; } c; c.i = ((unsigned int)u) << 16; return c.f;
}
__device__ __forceinline__ unsigned short f2bf(float f) {
  union { float f; unsigned int i; } c; c.f = f;
  unsigned int i = c.i;
  return (unsigned short)((i + 0x7fffu + ((i >> 16) & 1u)) >> 16);  // RNE
}
__device__ __forceinline__ float tanh_fast(float x) {
  float e2 = __expf(2.0f * x);
  return 1.0f - 2.0f / (e2 + 1.0f);
}
__device__ __forceinline__ float sigm(float x) {
  return 1.0f / (1.0f + __expf(-x));
}
__device__ __forceinline__ float wave_sum(float v) {
  #pragma unroll
  for (int o = 1; o < 64; o <<= 1) v += __shfl_xor(v, o, 64);
  return v;
}

// Group barrier: 32 wgs, sense via monotonically increasing generation.
// cnt at bar[g*64], gen at bar[g*64+32] (separate 128B lines per group).
__device__ __forceinline__ void group_barrier(unsigned* bar, int g, unsigned* lgen) {
  __syncthreads();
  if (threadIdx.x == 0) {
    unsigned* cnt = bar + g * 64;
    unsigned* gen = bar + g * 64 + 32;
    __threadfence();  // make this wg's global writes visible device-wide
    unsigned prev = __hip_atomic_fetch_add(cnt, 1u, __ATOMIC_ACQ_REL, __HIP_MEMORY_SCOPE_AGENT);
    if (prev == 31u) {
      __hip_atomic_store(cnt, 0u, __ATOMIC_RELAXED, __HIP_MEMORY_SCOPE_AGENT);
      __hip_atomic_fetch_add(gen, 1u, __ATOMIC_RELEASE, __HIP_MEMORY_SCOPE_AGENT);
    } else {
      unsigned cur = *lgen;
      while (__hip_atomic_load(gen, __ATOMIC_ACQUIRE, __HIP_MEMORY_SCOPE_AGENT) == cur) {
        __builtin_amdgcn_s_sleep(1);
      }
    }
    *lgen = *lgen + 1u;
  }
  __syncthreads();
}

__global__ void init_bar(unsigned* bar) {
  bar[threadIdx.x] = 0u;  // 512 words
}

__global__ __launch_bounds__(NT, 1)
void fused(const float* __restrict__ enc,      // (T,B,M)
           const float* __restrict__ yv,       // (B,T,1)
           const float* __restrict__ W_d,      // (M,2H)
           const float* __restrict__ b_Wd,     // (M)
           const float* __restrict__ U_d,      // (M,M)
           const float* __restrict__ v_d,      // (1,M)
           const float* __restrict__ w_tilda,  // (1,M+1)
           const float* __restrict__ b_wt,     // (1)
           const float* __restrict__ W_ih,     // (4H,1)
           const float* __restrict__ W_hh,     // (4H,H)
           const float* __restrict__ b_ih,     // (4H)
           const float* __restrict__ b_hh,     // (4H)
           const float* __restrict__ W_y,      // (H,H+M)
           const float* __restrict__ b_Wy,     // (H)
           const float* __restrict__ v_y,      // (1,H)
           const float* __restrict__ b_vy,     // (1)
           float* __restrict__ out,            // (B,1)
           unsigned* __restrict__ bar,         // 512 u32
           unsigned short* __restrict__ Y1,    // (B,T,M) bf16
           float* __restrict__ X1,             // (B,M)
           float* __restrict__ G1,             // (B,4H)
           float* __restrict__ D,              // (B,H)
           float* __restrict__ SP)             // (B,H)
{
  __shared__ unsigned short enc_s[Tx][Mx];  // 32 KB, bf16 enc[b]
  __shared__ float l_s[Tx];
  __shared__ float beta_s[Tx];
  __shared__ float red_s[8];
  __shared__ float ytil_s;
  __shared__ float dc_s[2 * Hx];

  const int w   = blockIdx.x;     // 0..255
  const int tid = threadIdx.x;    // 0..255
  const int g   = w >> 5;         // group 0..7
  const int s   = w & 31;         // slice in group
  const int b   = w;              // phase-2 batch element
  const int gb  = g << 5;         // group's first b
  const size_t BM = (size_t)Bx * Mx;

  // ---- preload enc[b] into LDS as bf16 (used by the c-reduction) ----
  for (int i = tid; i < Tx * Mx; i += NT) {
    int t = i >> 8, m = i & 255;
    enc_s[t][m] = f2bf(enc[(size_t)t * BM + (size_t)b * Mx + m]);
  }
  // ---- zero recurrent state ----
  D[b * Hx + tid]  = 0.0f;
  SP[b * Hx + tid] = 0.0f;

  // ---- one-time: Y1[b] = enc[b] @ U_d^T (fp32 math, bf16 store) ----
  {
    const int n = tid;
    const float* Ur = U_d + n * Mx;
    const float* eb = enc + (size_t)b * Mx;
    for (int tb = 0; tb < Tx; tb += 8) {
      float acc[8] = {0, 0, 0, 0, 0, 0, 0, 0};
      for (int m = 0; m < Mx; m += 4) {
        float4 u4 = ld4(Ur + m);
        #pragma unroll
        for (int j = 0; j < 8; ++j) {
          float4 e4 = ld4(eb + (size_t)(tb + j) * BM + m);  // lane-uniform -> L1 broadcast
          acc[j] += dot4(e4, u4);
        }
      }
      #pragma unroll
      for (int j = 0; j < 8; ++j)
        Y1[((size_t)b * Tx + tb + j) * Mx + n] = f2bf(acc[j]);
    }
  }

  unsigned lgen = 0;
  group_barrier(bar, g, &lgen);  // D/SP zeroed group-wide

  float sp_reg = 0.0f;  // this thread's sp[b][tid]
  float cm = 0.0f;      // this thread's c[b][tid] (kept for final step)

  for (int t = 0; t < Tx; ++t) {
    // ================= Phase 1: weight GEMMs, B-tiled across group =========
    {
      const int bl = tid >> 3;       // 0..31: which b of the group
      const int nl = tid & 7;        // 0..7
      const int bb = gb + bl;
      const float* dr  = D  + bb * Hx;
      const float* spr = SP + bb * Hx;
      // --- x1[bb][n] for n = s*8 + nl (K = 2H over [d|sp]) ---
      {
        const int n = (s << 3) + nl;
        const float* wr = W_d + n * (2 * Hx);
        float a = b_Wd[n];
        for (int k = 0; k < Hx; k += 4) {
          float4 d4  = ld4(dr + k);
          float4 w4  = ld4(wr + k);
          float4 s4  = ld4(spr + k);
          float4 w24 = ld4(wr + Hx + k);
          a += dot4(d4, w4) + dot4(s4, w24);
        }
        X1[bb * Mx + n] = a;
      }
      // --- g1[bb][j] for j = s*32 + nl + {0,8,16,24} (K = H over d) ---
      {
        const int j0 = (s << 5) + nl;
        const float* w0 = W_hh + (size_t)(j0)      * Hx;
        const float* w1 = W_hh + (size_t)(j0 + 8)  * Hx;
        const float* w2 = W_hh + (size_t)(j0 + 16) * Hx;
        const float* w3 = W_hh + (size_t)(j0 + 24) * Hx;
        float a0 = b_ih[j0]      + b_hh[j0];
        float a1 = b_ih[j0 + 8]  + b_hh[j0 + 8];
        float a2 = b_ih[j0 + 16] + b_hh[j0 + 16];
        float a3 = b_ih[j0 + 24] + b_hh[j0 + 24];
        for (int k = 0; k < Hx; k += 4) {
          float4 d4 = ld4(dr + k);
          a0 += dot4(d4, ld4(w0 + k));
          a1 += dot4(d4, ld4(w1 + k));
          a2 += dot4(d4, ld4(w2 + k));
          a3 += dot4(d4, ld4(w3 + k));
        }
        float* gr = G1 + (size_t)bb * 4 * Hx;
        gr[j0] = a0; gr[j0 + 8] = a1; gr[j0 + 16] = a2; gr[j0 + 24] = a3;
      }
    }
    group_barrier(bar, g, &lgen);  // X1, G1 ready

    // ================= Phase 2: attention + LSTM for b = w ==================
    // scores: l[tq] = sum_m tanh(x1[m] + y1[tq][m]) * v_d[m]; 4 lanes per tq
    {
      const int tq = tid >> 2, lq = tid & 3;
      const float* x1r = X1 + b * Mx + lq * 64;
      const float* vdr = v_d + lq * 64;
      const unsigned short* y1r = Y1 + ((size_t)b * Tx + tq) * Mx + lq * 64;
      float p = 0.0f;
      for (int mi = 0; mi < 64; mi += 8) {
        uint4 q = *(const uint4*)(y1r + mi);
        float4 xa = ld4(x1r + mi), xb = ld4(x1r + mi + 4);
        float4 va = ld4(vdr + mi), vb = ld4(vdr + mi + 4);
        float y0 = bf2f((unsigned short)(q.x & 0xffffu));
        float y1f = bf2f((unsigned short)(q.x >> 16));
        float y2 = bf2f((unsigned short)(q.y & 0xffffu));
        float y3 = bf2f((unsigned short)(q.y >> 16));
        float y4 = bf2f((unsigned short)(q.z & 0xffffu));
        float y5 = bf2f((unsigned short)(q.z >> 16));
        float y6 = bf2f((unsigned short)(q.w & 0xffffu));
        float y7 = bf2f((unsigned short)(q.w >> 16));
        p += tanh_fast(xa.x + y0) * va.x + tanh_fast(xa.y + y1f) * va.y
           + tanh_fast(xa.z + y2) * va.z + tanh_fast(xa.w + y3) * va.w
           + tanh_fast(xb.x + y4) * vb.x + tanh_fast(xb.y + y5) * vb.y
           + tanh_fast(xb.z + y6) * vb.z + tanh_fast(xb.w + y7) * vb.w;
      }
      p += __shfl_xor(p, 1, 64);
      p += __shfl_xor(p, 2, 64);
      if (lq == 0) l_s[tq] = p;
    }
    __syncthreads();
    // softmax over T=64 in the first wave
    if (tid < 64) {
      float v = l_s[tid];
      float mx = v;
      #pragma unroll
      for (int o = 1; o < 64; o <<= 1) mx = fmaxf(mx, __shfl_xor(mx, o, 64));
      float e = __expf(v - mx);
      float sm = e;
      #pragma unroll
      for (int o = 1; o < 64; o <<= 1) sm += __shfl_xor(sm, o, 64);
      beta_s[tid] = e / sm;
    }
    __syncthreads();
    // c[m] and y_til
    cm = 0.0f;
    for (int tt = 0; tt < Tx; ++tt)
      cm += beta_s[tt] * bf2f(enc_s[tt][tid]);
    {
      float pt = cm * w_tilda[tid];
      float wsum = wave_sum(pt);
      if ((tid & 63) == 0) red_s[tid >> 6] = wsum;
      __syncthreads();
      if (tid == 0) {
        float yt = red_s[0] + red_s[1] + red_s[2] + red_s[3];
        yt += w_tilda[Mx] * yv[b * Tx + t] + b_wt[0];
        ytil_s = yt;
      }
      __syncthreads();
    }
    // LSTM cell: thread tid = h
    {
      const float ytil = ytil_s;
      const float* gr = G1 + (size_t)b * 4 * Hx;
      float gi = gr[tid]       + ytil * W_ih[tid];
      float gf = gr[256 + tid] + ytil * W_ih[256 + tid];
      float gg = gr[512 + tid] + ytil * W_ih[512 + tid];
      float go = gr[768 + tid] + ytil * W_ih[768 + tid];
      float fi = sigm(gi), ff = sigm(gf), fg = tanh_fast(gg), fo = sigm(go);
      float spn = ff * sp_reg + fi * fg;
      float dn  = fo * tanh_fast(spn);
      sp_reg = spn;
      D[b * Hx + tid]  = dn;
      SP[b * Hx + tid] = spn;
      if (t == Tx - 1) { dc_s[tid] = dn; dc_s[Hx + tid] = cm; }
    }
    group_barrier(bar, g, &lgen);  // D/SP ready for next step
  }

  // ================= Final: out[b] = v_y . (W_y @ [d|c] + b_Wy) + b_vy =====
  {
    const float* wyr = W_y + (size_t)tid * (Hx + Mx);
    float a = b_Wy[tid];
    for (int k = 0; k < Hx + Mx; k += 4) {
      float4 w4 = ld4(wyr + k);
      a += dc_s[k] * w4.x + dc_s[k + 1] * w4.y + dc_s[k + 2] * w4.z + dc_s[k + 3] * w4.w;
    }
    float po = a * v_y[tid];
    float wsum = wave_sum(po);
    if ((tid & 63) == 0) red_s[tid >> 6] = wsum;
    __syncthreads();
    if (tid == 0) out[b] = red_s[0] + red_s[1] + red_s[2] + red_s[3] + b_vy[0];
  }
}

extern "C" void kernel_launch(void* const* d_in, const int* in_sizes, int n_in,
                              void* d_out, int out_size, void* d_ws, size_t ws_size,
                              hipStream_t stream) {
  const float* enc     = (const float*)d_in[0];
  const float* yv      = (const float*)d_in[1];
  const float* W_d     = (const float*)d_in[2];
  const float* b_Wd    = (const float*)d_in[3];
  const float* U_d     = (const float*)d_in[4];
  const float* v_d     = (const float*)d_in[5];
  const float* w_tilda = (const float*)d_in[6];
  const float* b_wt    = (const float*)d_in[7];
  const float* W_ih    = (const float*)d_in[8];
  const float* W_hh    = (const float*)d_in[9];
  const float* b_ih    = (const float*)d_in[10];
  const float* b_hh    = (const float*)d_in[11];
  const float* W_y     = (const float*)d_in[12];
  const float* b_Wy    = (const float*)d_in[13];
  const float* v_y     = (const float*)d_in[14];
  const float* b_vy    = (const float*)d_in[15];
  float* outp = (float*)d_out;

  char* ws = (char*)d_ws;
  unsigned* bar       = (unsigned*)ws;                          // 2048 B
  unsigned short* Y1  = (unsigned short*)(ws + 2048);           // 8 MB bf16
  float* X1 = (float*)(ws + 2048 + (size_t)Bx * Tx * Mx * 2);   // 256 KB
  float* G1 = X1 + (size_t)Bx * Mx;                             // 1 MB
  float* D  = G1 + (size_t)Bx * 4 * Hx;                         // 256 KB
  float* SP = D  + (size_t)Bx * Hx;                             // 256 KB

  hipLaunchKernelGGL(init_bar, dim3(1), dim3(512), 0, stream, bar);

  void* args[] = { (void*)&enc, (void*)&yv, (void*)&W_d, (void*)&b_Wd,
                   (void*)&U_d, (void*)&v_d, (void*)&w_tilda, (void*)&b_wt,
                   (void*)&W_ih, (void*)&W_hh, (void*)&b_ih, (void*)&b_hh,
                   (void*)&W_y, (void*)&b_Wy, (void*)&v_y, (void*)&b_vy,
                   (void*)&outp, (void*)&bar, (void*)&Y1, (void*)&X1,
                   (void*)&G1, (void*)&D, (void*)&SP };
  hipLaunchCooperativeKernel((void*)fused, dim3(NB), dim3(NT), args, 0, stream);
}

// Round 2
// 2245.263 us; speedup vs baseline: 2.9936x; 2.9936x over previous
//
#include <hip/hip_runtime.h>

// ---------------------------------------------------------------------------
// TemporalAttnLayer: B=256, T=64, M=256, H=256
//
// Round-2 design: ZERO inter-workgroup communication.
//  - 256 independent wgs (1 per batch element), 256 threads each, plain launch.
//  - Weights pre-packed to bf16 in k-major (transposed) layout by a pack
//    kernel -> recurrent GEMVs read them fully coalesced (uint2 = 4 bf16/lane).
//  - Per step per wg: x1=[d|sp]@W_d.T fused with g1=d@W_hh.T over the shared
//    d-half of K; gates live in registers across phases (thread h owns the 4
//    gates of neuron h). d/sp in LDS. Attention reads y1[b] (bf16, global ws,
//    wg-private) + enc[b] (bf16, LDS, transposed). No fences, no atomics.
//  - Weight traffic 768KB/step/wg, L2-resident -> ~5.5us/step expected.
// ---------------------------------------------------------------------------

#define Bx 256
#define Tx 64
#define Mx 256
#define Hx 256
#define NT 256
#define ETS 66   // encT_s row stride (ushorts), +2 pad breaks bank conflicts

__device__ __forceinline__ float4 ld4(const float* p) { return *(const float4*)p; }
__device__ __forceinline__ float bfl(unsigned int u) {
  union { unsigned int i; float f; } c; c.i = u << 16; return c.f;
}
__device__ __forceinline__ float bfh(unsigned int u) {
  union { unsigned int i; float f; } c; c.i = u & 0xffff0000u; return c.f;
}
__device__ __forceinline__ float bf2f(unsigned short u) {
  union { unsigned int i; float f; } c; c.i = ((unsigned int)u) << 16; return c.f;
}
__device__ __forceinline__ unsigned short f2bf(float f) {
  union { float f; unsigned int i; } c; c.f = f;
  unsigned int i = c.i;
  return (unsigned short)((i + 0x7fffu + ((i >> 16) & 1u)) >> 16);  // RNE
}
__device__ __forceinline__ float tanh_fast(float x) {
  float e2 = __expf(2.0f * x);
  return 1.0f - 2.0f / (e2 + 1.0f);
}
__device__ __forceinline__ float sigm(float x) {
  return 1.0f / (1.0f + __expf(-x));
}
__device__ __forceinline__ float wave_sum(float v) {
  #pragma unroll
  for (int o = 1; o < 64; o <<= 1) v += __shfl_xor(v, o, 64);
  return v;
}

// ---------------------------------------------------------------------------
// Pack kernel: fp32 weights -> bf16, k-major (coalesced for GEMV).
//   Wd4 [k4][n]  k4<128 : uint2 = W_d[n][4k4..4k4+3]     (256 KB)
//   Whh4[k4][j]  k4<64  : uint2 = W_hh[j][4k4..4k4+3]    (512 KB)
//   Ud4 [m4][n]  m4<64  : uint2 = U_d[n][4m4..4m4+3]     (128 KB)
// grid 256 x 256
// ---------------------------------------------------------------------------
__global__ __launch_bounds__(NT)
void pack_weights(const float* __restrict__ W_d,
                  const float* __restrict__ W_hh,
                  const float* __restrict__ U_d,
                  uint2* __restrict__ Wd4,
                  uint2* __restrict__ Whh4,
                  uint2* __restrict__ Ud4) {
  const int blk = blockIdx.x, tid = threadIdx.x;
  if (blk < 128) {                       // Wd: k4 = blk, n = tid
    const int k4 = blk;
    float4 w = ld4(W_d + (size_t)tid * 512 + 4 * k4);
    uint2 u;
    u.x = (unsigned)f2bf(w.x) | ((unsigned)f2bf(w.y) << 16);
    u.y = (unsigned)f2bf(w.z) | ((unsigned)f2bf(w.w) << 16);
    Wd4[k4 * 256 + tid] = u;
  } else if (blk < 192) {                // Whh: k4 = blk-128, j = tid + 256q
    const int k4 = blk - 128;
    #pragma unroll
    for (int q = 0; q < 4; ++q) {
      const int j = tid + 256 * q;
      float4 w = ld4(W_hh + (size_t)j * 256 + 4 * k4);
      uint2 u;
      u.x = (unsigned)f2bf(w.x) | ((unsigned)f2bf(w.y) << 16);
      u.y = (unsigned)f2bf(w.z) | ((unsigned)f2bf(w.w) << 16);
      Whh4[k4 * 1024 + j] = u;
    }
  } else {                               // Ud: m4 = blk-192, n = tid
    const int m4 = blk - 192;
    float4 w = ld4(U_d + (size_t)tid * 256 + 4 * m4);
    uint2 u;
    u.x = (unsigned)f2bf(w.x) | ((unsigned)f2bf(w.y) << 16);
    u.y = (unsigned)f2bf(w.z) | ((unsigned)f2bf(w.w) << 16);
    Ud4[m4 * 256 + tid] = u;
  }
}

// ---------------------------------------------------------------------------
// Main kernel: one wg per batch element, fully independent.
// ---------------------------------------------------------------------------
__global__ __launch_bounds__(NT, 1)
void fused(const float* __restrict__ enc,      // (T,B,M)
           const float* __restrict__ yv,       // (B,T,1)
           const float* __restrict__ b_Wd,     // (M)
           const float* __restrict__ v_d,      // (1,M)
           const float* __restrict__ w_tilda,  // (1,M+1)
           const float* __restrict__ b_wt,     // (1)
           const float* __restrict__ W_ih,     // (4H,1)
           const float* __restrict__ b_ih,     // (4H)
           const float* __restrict__ b_hh,     // (4H)
           const float* __restrict__ W_y,      // (H,H+M)
           const float* __restrict__ b_Wy,     // (H)
           const float* __restrict__ v_y,      // (1,H)
           const float* __restrict__ b_vy,     // (1)
           const uint2* __restrict__ Wd4,      // packed
           const uint2* __restrict__ Whh4,     // packed
           const uint2* __restrict__ Ud4,      // packed
           unsigned short* __restrict__ Y1,    // (B,T,M) bf16 scratch
           float* __restrict__ out)            // (B,1)
{
  __shared__ unsigned short encT_s[Mx * ETS];  // [m][t], bf16, 33.8 KB
  __shared__ float dsp_s[2 * Hx];              // [d | sp] (then [d | c] at end)
  __shared__ float x1_s[Mx];
  __shared__ float l_s[Tx];
  __shared__ float beta_s[Tx];
  __shared__ float red_s[4];
  __shared__ float ytil_s;

  const int b   = blockIdx.x;
  const int tid = threadIdx.x;
  const size_t BM = (size_t)Bx * Mx;

  // ---- stage 0: enc[b] -> LDS transposed bf16 ----
  for (int i = tid; i < Tx * Mx; i += NT) {
    int t = i >> 8, m = i & 255;
    encT_s[m * ETS + t] = f2bf(enc[(size_t)t * BM + (size_t)b * Mx + m]);
  }
  // state init
  dsp_s[tid] = 0.0f;
  dsp_s[Hx + tid] = 0.0f;

  // ---- per-thread cached parameters ----
  const float bWd_r = b_Wd[tid];
  const float b4r0 = b_ih[tid]       + b_hh[tid];
  const float b4r1 = b_ih[tid + 256] + b_hh[tid + 256];
  const float b4r2 = b_ih[tid + 512] + b_hh[tid + 512];
  const float b4r3 = b_ih[tid + 768] + b_hh[tid + 768];
  const float wih0 = W_ih[tid], wih1 = W_ih[tid + 256];
  const float wih2 = W_ih[tid + 512], wih3 = W_ih[tid + 768];
  const float wt_r = w_tilda[tid];
  const float wty  = w_tilda[Mx];
  const float bwt  = b_wt[0];

  // ---- stage 1: Y1[b] = enc[b] @ U_d^T  (bf16 weights, fp32 enc broadcast) ----
  {
    const int n = tid;
    const float* eb = enc + (size_t)b * Mx;
    for (int tb = 0; tb < Tx; tb += 8) {
      float acc[8] = {0, 0, 0, 0, 0, 0, 0, 0};
      for (int m4 = 0; m4 < 64; ++m4) {
        uint2 u = Ud4[m4 * 256 + n];  // coalesced
        float w0 = bfl(u.x), w1 = bfh(u.x), w2 = bfl(u.y), w3 = bfh(u.y);
        #pragma unroll
        for (int j = 0; j < 8; ++j) {
          float4 e4 = ld4(eb + (size_t)(tb + j) * BM + 4 * m4);  // lane-uniform
          acc[j] += e4.x * w0 + e4.y * w1 + e4.z * w2 + e4.w * w3;
        }
      }
      #pragma unroll
      for (int j = 0; j < 8; ++j)
        Y1[((size_t)b * Tx + tb + j) * Mx + n] = f2bf(acc[j]);
    }
  }
  __syncthreads();  // encT_s + dsp_s ready

  float sp_reg = 0.0f;
  float cm = 0.0f;

  for (int t = 0; t < Tx; ++t) {
    // ========= Phase A: x1 = [d|sp]@W_d.T + b_Wd ; gates = d@W_hh.T + biases
    {
      float xacc = bWd_r;
      float g0 = b4r0, g1 = b4r1, g2 = b4r2, g3 = b4r3;
      const uint2* whh_t = Whh4 + tid;
      const uint2* wd_t  = Wd4 + tid;
      #pragma unroll 2
      for (int k4 = 0; k4 < 64; ++k4) {  // d-half: fused x1 + gates
        float4 d4 = *(const float4*)&dsp_s[k4 * 4];
        uint2 wx  = wd_t[k4 * 256];
        uint2 w0  = whh_t[k4 * 1024];
        uint2 w1  = whh_t[k4 * 1024 + 256];
        uint2 w2  = whh_t[k4 * 1024 + 512];
        uint2 w3  = whh_t[k4 * 1024 + 768];
        xacc += d4.x * bfl(wx.x) + d4.y * bfh(wx.x) + d4.z * bfl(wx.y) + d4.w * bfh(wx.y);
        g0 += d4.x * bfl(w0.x) + d4.y * bfh(w0.x) + d4.z * bfl(w0.y) + d4.w * bfh(w0.y);
        g1 += d4.x * bfl(w1.x) + d4.y * bfh(w1.x) + d4.z * bfl(w1.y) + d4.w * bfh(w1.y);
        g2 += d4.x * bfl(w2.x) + d4.y * bfh(w2.x) + d4.z * bfl(w2.y) + d4.w * bfh(w2.y);
        g3 += d4.x * bfl(w3.x) + d4.y * bfh(w3.x) + d4.z * bfl(w3.y) + d4.w * bfh(w3.y);
      }
      #pragma unroll 4
      for (int k4 = 64; k4 < 128; ++k4) {  // sp-half: x1 only
        float4 s4 = *(const float4*)&dsp_s[k4 * 4];
        uint2 wx  = wd_t[k4 * 256];
        xacc += s4.x * bfl(wx.x) + s4.y * bfh(wx.x) + s4.z * bfl(wx.y) + s4.w * bfh(wx.y);
      }
      x1_s[tid] = xacc;
      // keep g0..g3 live for Phase C
      __syncthreads();  // x1_s ready (dsp_s reads done)

      // ========= Phase B: attention scores, softmax, context =========
      // scores: quad (4 lanes) per t-query over M=256
      {
        const int tq = tid >> 2, lq = tid & 3;
        const float* x1r = x1_s + lq * 64;
        const float* vdr = v_d + lq * 64;
        const unsigned short* y1r = Y1 + ((size_t)b * Tx + tq) * Mx + lq * 64;
        float p = 0.0f;
        #pragma unroll
        for (int mi = 0; mi < 64; mi += 8) {
          uint4 q = *(const uint4*)(y1r + mi);
          float4 xa = *(const float4*)(x1r + mi);
          float4 xb = *(const float4*)(x1r + mi + 4);
          float4 va = ld4(vdr + mi), vb = ld4(vdr + mi + 4);
          p += tanh_fast(xa.x + bfl(q.x)) * va.x + tanh_fast(xa.y + bfh(q.x)) * va.y
             + tanh_fast(xa.z + bfl(q.y)) * va.z + tanh_fast(xa.w + bfh(q.y)) * va.w
             + tanh_fast(xb.x + bfl(q.z)) * vb.x + tanh_fast(xb.y + bfh(q.z)) * vb.y
             + tanh_fast(xb.z + bfl(q.w)) * vb.z + tanh_fast(xb.w + bfh(q.w)) * vb.w;
        }
        p += __shfl_xor(p, 1, 64);
        p += __shfl_xor(p, 2, 64);
        if (lq == 0) l_s[tq] = p;
      }
      __syncthreads();
      if (tid < 64) {  // softmax over T in wave 0
        float v = l_s[tid];
        float mx = v;
        #pragma unroll
        for (int o = 1; o < 64; o <<= 1) mx = fmaxf(mx, __shfl_xor(mx, o, 64));
        float e = __expf(v - mx);
        float sm = e;
        #pragma unroll
        for (int o = 1; o < 64; o <<= 1) sm += __shfl_xor(sm, o, 64);
        beta_s[tid] = e / sm;
      }
      __syncthreads();
      // context c[m], m = tid
      cm = 0.0f;
      {
        const unsigned short* er = encT_s + tid * ETS;
        #pragma unroll 8
        for (int tt = 0; tt < Tx; ++tt)
          cm += beta_s[tt] * bf2f(er[tt]);
      }
      // y_til (scalar)
      {
        float pt = cm * wt_r;
        float ws = wave_sum(pt);
        if ((tid & 63) == 0) red_s[tid >> 6] = ws;
        __syncthreads();
        if (tid == 0)
          ytil_s = red_s[0] + red_s[1] + red_s[2] + red_s[3]
                 + wty * yv[b * Tx + t] + bwt;
        __syncthreads();
      }
      // ========= Phase C: LSTM cell (gates already in registers) =========
      {
        const float ytil = ytil_s;
        float fi = sigm(g0 + ytil * wih0);
        float ff = sigm(g1 + ytil * wih1);
        float fg = tanh_fast(g2 + ytil * wih2);
        float fo = sigm(g3 + ytil * wih3);
        float spn = ff * sp_reg + fi * fg;
        float dn  = fo * tanh_fast(spn);
        sp_reg = spn;
        dsp_s[tid] = dn;
        dsp_s[Hx + tid] = (t == Tx - 1) ? cm : spn;  // final step: [d|c]
      }
      __syncthreads();  // dsp_s ready for next step
    }
  }

  // ========= Epilogue: out[b] = v_y . (W_y @ [d|c] + b_Wy) + b_vy =========
  {
    const float* wyr = W_y + (size_t)tid * (Hx + Mx);
    float a = b_Wy[tid];
    for (int k = 0; k < Hx + Mx; k += 4) {
      float4 w4 = ld4(wyr + k);
      a += dsp_s[k] * w4.x + dsp_s[k + 1] * w4.y + dsp_s[k + 2] * w4.z + dsp_s[k + 3] * w4.w;
    }
    float po = a * v_y[tid];
    float ws = wave_sum(po);
    if ((tid & 63) == 0) red_s[tid >> 6] = ws;
    __syncthreads();
    if (tid == 0) out[b] = red_s[0] + red_s[1] + red_s[2] + red_s[3] + b_vy[0];
  }
}

extern "C" void kernel_launch(void* const* d_in, const int* in_sizes, int n_in,
                              void* d_out, int out_size, void* d_ws, size_t ws_size,
                              hipStream_t stream) {
  const float* enc     = (const float*)d_in[0];
  const float* yv      = (const float*)d_in[1];
  const float* W_d     = (const float*)d_in[2];
  const float* b_Wd    = (const float*)d_in[3];
  const float* U_d     = (const float*)d_in[4];
  const float* v_d     = (const float*)d_in[5];
  const float* w_tilda = (const float*)d_in[6];
  const float* b_wt    = (const float*)d_in[7];
  const float* W_ih    = (const float*)d_in[8];
  const float* W_hh    = (const float*)d_in[9];
  const float* b_ih    = (const float*)d_in[10];
  const float* b_hh    = (const float*)d_in[11];
  const float* W_y     = (const float*)d_in[12];
  const float* b_Wy    = (const float*)d_in[13];
  const float* v_y     = (const float*)d_in[14];
  const float* b_vy    = (const float*)d_in[15];
  float* outp = (float*)d_out;

  char* ws = (char*)d_ws;
  uint2* Wd4  = (uint2*)ws;                        // 256 KB
  uint2* Whh4 = (uint2*)(ws + (256 << 10));        // 512 KB
  uint2* Ud4  = (uint2*)(ws + (768 << 10));        // 128 KB
  unsigned short* Y1 = (unsigned short*)(ws + (896 << 10));  // 8 MB

  hipLaunchKernelGGL(pack_weights, dim3(256), dim3(NT), 0, stream,
                     W_d, W_hh, U_d, Wd4, Whh4, Ud4);
  hipLaunchKernelGGL(fused, dim3(Bx), dim3(NT), 0, stream,
                     enc, yv, b_Wd, v_d, w_tilda, b_wt, W_ih, b_ih, b_hh,
                     W_y, b_Wy, v_y, b_vy, Wd4, Whh4, Ud4, Y1, outp);
}

// Round 3
// 1216.814 us; speedup vs baseline: 5.5238x; 1.8452x over previous
//
#include <hip/hip_runtime.h>

// ---------------------------------------------------------------------------
// TemporalAttnLayer: B=256, T=64, M=256, H=256
//
// Round-3: round-2 structure (zero inter-wg communication, bf16-packed
// weights streamed from L2) but 1024-thread workgroups -> 16 waves/CU
// (4/SIMD) for latency hiding. Per-thread work cut 4x:
//   - gates: output-split, thread tid owns gate j=tid (K=256, coalesced)
//   - x1:    K-split into 4 quarters (thread h,p), LDS reduce
//   - scores: 16 lanes/query, in-wave shuffle reduce
//   - context: 4-way t-split inside the wave, shuffle reduce
// Bank-conflict fixes: x1/v_d in swizzled stride-18 chunks (float2 reads).
// ---------------------------------------------------------------------------

#define Bx 256
#define Tx 64
#define Mx 256
#define Hx 256
#define NT 1024
#define ETS 66    // encT_s row stride in ushorts (bank-conflict-free, 4B align)
#define XS 18     // swizzled chunk stride for x1/v_d (16 payload + 2 pad)

__device__ __forceinline__ float4 ld4(const float* p) { return *(const float4*)p; }
__device__ __forceinline__ float bfl(unsigned int u) {
  union { unsigned int i; float f; } c; c.i = u << 16; return c.f;
}
__device__ __forceinline__ float bfh(unsigned int u) {
  union { unsigned int i; float f; } c; c.i = u & 0xffff0000u; return c.f;
}
__device__ __forceinline__ float bf2f(unsigned short u) {
  union { unsigned int i; float f; } c; c.i = ((unsigned int)u) << 16; return c.f;
}
__device__ __forceinline__ unsigned short f2bf(float f) {
  union { float f; unsigned int i; } c; c.f = f;
  unsigned int i = c.i;
  return (unsigned short)((i + 0x7fffu + ((i >> 16) & 1u)) >> 16);  // RNE
}
__device__ __forceinline__ float tanh_fast(float x) {
  float e2 = __expf(2.0f * x);
  return 1.0f - 2.0f / (e2 + 1.0f);
}
__device__ __forceinline__ float sigm(float x) {
  return 1.0f / (1.0f + __expf(-x));
}
__device__ __forceinline__ float wave_sum(float v) {
  #pragma unroll
  for (int o = 1; o < 64; o <<= 1) v += __shfl_xor(v, o, 64);
  return v;
}
__device__ __forceinline__ int xsw(int m) { return (m >> 4) * XS + (m & 15); }

// ---------------------------------------------------------------------------
// Pack kernel: fp32 weights -> bf16 k-major; W_y -> fp32 transposed.
//   Wd4 [k4][n]  k4<128 : uint2 = W_d[n][4k4..+3]    (256 KB)
//   Whh4[k4][j]  k4<64  : uint2 = W_hh[j][4k4..+3]   (512 KB)
//   Ud4 [m4][n]  m4<64  : uint2 = U_d[n][4m4..+3]    (128 KB)
//   Wyt [k][h]   k<512  : float = W_y[h][k]          (512 KB)
// grid 384 x 256
// ---------------------------------------------------------------------------
__global__ __launch_bounds__(256)
void pack_weights(const float* __restrict__ W_d,
                  const float* __restrict__ W_hh,
                  const float* __restrict__ U_d,
                  const float* __restrict__ W_y,
                  uint2* __restrict__ Wd4,
                  uint2* __restrict__ Whh4,
                  uint2* __restrict__ Ud4,
                  float* __restrict__ Wyt) {
  const int blk = blockIdx.x, tid = threadIdx.x;
  if (blk < 128) {                       // Wd
    const int k4 = blk;
    float4 w = ld4(W_d + (size_t)tid * 512 + 4 * k4);
    uint2 u;
    u.x = (unsigned)f2bf(w.x) | ((unsigned)f2bf(w.y) << 16);
    u.y = (unsigned)f2bf(w.z) | ((unsigned)f2bf(w.w) << 16);
    Wd4[k4 * 256 + tid] = u;
  } else if (blk < 192) {                // Whh
    const int k4 = blk - 128;
    #pragma unroll
    for (int q = 0; q < 4; ++q) {
      const int j = tid + 256 * q;
      float4 w = ld4(W_hh + (size_t)j * 256 + 4 * k4);
      uint2 u;
      u.x = (unsigned)f2bf(w.x) | ((unsigned)f2bf(w.y) << 16);
      u.y = (unsigned)f2bf(w.z) | ((unsigned)f2bf(w.w) << 16);
      Whh4[k4 * 1024 + j] = u;
    }
  } else if (blk < 256) {                // Ud
    const int m4 = blk - 192;
    float4 w = ld4(U_d + (size_t)tid * 256 + 4 * m4);
    uint2 u;
    u.x = (unsigned)f2bf(w.x) | ((unsigned)f2bf(w.y) << 16);
    u.y = (unsigned)f2bf(w.z) | ((unsigned)f2bf(w.w) << 16);
    Ud4[m4 * 256 + tid] = u;
  } else {                               // Wyt: transpose W_y
    const int k0 = (blk - 256) * 4;      // 4 k-rows per block
    float4 w = ld4(W_y + (size_t)tid * 512 + k0);
    Wyt[(k0 + 0) * 256 + tid] = w.x;
    Wyt[(k0 + 1) * 256 + tid] = w.y;
    Wyt[(k0 + 2) * 256 + tid] = w.z;
    Wyt[(k0 + 3) * 256 + tid] = w.w;
  }
}

// ---------------------------------------------------------------------------
// Main kernel: one 1024-thread wg per batch element, fully independent.
// ---------------------------------------------------------------------------
__global__ __launch_bounds__(NT)
void fused(const float* __restrict__ enc,      // (T,B,M)
           const float* __restrict__ yv,       // (B,T,1)
           const float* __restrict__ b_Wd,     // (M)
           const float* __restrict__ v_d,      // (1,M)
           const float* __restrict__ w_tilda,  // (1,M+1)
           const float* __restrict__ b_wt,     // (1)
           const float* __restrict__ W_ih,     // (4H,1)
           const float* __restrict__ b_ih,     // (4H)
           const float* __restrict__ b_hh,     // (4H)
           const float* __restrict__ b_Wy,     // (H)
           const float* __restrict__ v_y,      // (1,H)
           const float* __restrict__ b_vy,     // (1)
           const uint2* __restrict__ Wd4,
           const uint2* __restrict__ Whh4,
           const uint2* __restrict__ Ud4,
           const float* __restrict__ Wyt,
           unsigned short* __restrict__ Y1,    // (B,T,M) bf16 scratch
           float* __restrict__ out)            // (B,1)
{
  __shared__ unsigned short encT_s[Mx * ETS];  // 33.8 KB  [m][t] bf16
  __shared__ float dsp_s[2 * Hx];              // [d | sp]
  __shared__ float x1_s[16 * XS];              // swizzled x1
  __shared__ float vd_s[16 * XS];              // swizzled v_d
  __shared__ float xpart_s[4 * 256];           // x1 K-split partials / epilogue
  __shared__ float gates_s[1024];
  __shared__ float c_s[256];
  __shared__ float l_s[Tx];
  __shared__ float beta_s[Tx];
  __shared__ float red_s[16];
  __shared__ float ytil_s;

  const int b   = blockIdx.x;
  const int tid = threadIdx.x;     // 0..1023
  const int h   = tid & 255;
  const int p   = tid >> 8;        // 0..3
  const size_t BM = (size_t)Bx * Mx;

  // ---- stage 0: enc[b] -> LDS transposed bf16; init state; cache v_d ----
  for (int i = tid; i < Tx * Mx; i += NT) {
    int t = i >> 8, m = i & 255;
    encT_s[m * ETS + t] = f2bf(enc[(size_t)t * BM + (size_t)b * Mx + m]);
  }
  if (tid < 256) {
    dsp_s[tid] = 0.0f;
    dsp_s[Hx + tid] = 0.0f;
    vd_s[xsw(tid)] = v_d[tid];
  }

  // ---- per-thread cached parameters ----
  const float bj   = b_ih[tid] + b_hh[tid];         // bias of gate j = tid
  const float wtm  = w_tilda[tid >> 2];             // context-thread's w_tilda
  float bWd_r = 0.f, wih0 = 0.f, wih1 = 0.f, wih2 = 0.f, wih3 = 0.f;
  if (tid < 256) {
    bWd_r = b_Wd[h];
    wih0 = W_ih[h]; wih1 = W_ih[h + 256]; wih2 = W_ih[h + 512]; wih3 = W_ih[h + 768];
  }
  const float wty = w_tilda[Mx];
  const float bwt = b_wt[0];

  // ---- stage 1: Y1[b] = enc[b] @ U_d^T, t-rows split by p ----
  {
    const int n = h;
    const float* eb = enc + (size_t)b * Mx;
    for (int tb = p * 16; tb < p * 16 + 16; tb += 8) {
      float acc[8] = {0, 0, 0, 0, 0, 0, 0, 0};
      for (int m4 = 0; m4 < 64; ++m4) {
        uint2 u = Ud4[m4 * 256 + n];
        float w0 = bfl(u.x), w1 = bfh(u.x), w2 = bfl(u.y), w3 = bfh(u.y);
        #pragma unroll
        for (int j = 0; j < 8; ++j) {
          float4 e4 = ld4(eb + (size_t)(tb + j) * BM + 4 * m4);  // wave-uniform
          acc[j] += e4.x * w0 + e4.y * w1 + e4.z * w2 + e4.w * w3;
        }
      }
      #pragma unroll
      for (int j = 0; j < 8; ++j)
        Y1[((size_t)b * Tx + tb + j) * Mx + n] = f2bf(acc[j]);
    }
  }
  __syncthreads();  // encT_s, dsp_s, vd_s, Y1 ready

  float sp_reg = 0.0f;   // valid for tid < 256 (thread h)

  for (int t = 0; t < Tx; ++t) {
    // ===== Phase A: gates (output-split) + x1 (K-split) =====
    {
      // gate j = tid: g = b_ih[j]+b_hh[j] + d . W_hh[j]
      float g = bj;
      const uint2* wp = Whh4 + tid;
      #pragma unroll 8
      for (int k4 = 0; k4 < 64; ++k4) {
        float4 d4 = *(const float4*)&dsp_s[k4 * 4];   // broadcast
        uint2 w = wp[k4 * 1024];                       // coalesced
        g += d4.x * bfl(w.x) + d4.y * bfh(w.x) + d4.z * bfl(w.y) + d4.w * bfh(w.y);
      }
      gates_s[tid] = g;
      // x1[h] partial over k4 in [32p, 32p+32)  (K=512 over [d|sp])
      float xa = 0.0f;
      const uint2* xp = Wd4 + h;
      #pragma unroll 8
      for (int k4 = 32 * p; k4 < 32 * p + 32; ++k4) {
        float4 s4 = *(const float4*)&dsp_s[k4 * 4];   // broadcast
        uint2 w = xp[k4 * 256];                        // coalesced
        xa += s4.x * bfl(w.x) + s4.y * bfh(w.x) + s4.z * bfl(w.y) + s4.w * bfh(w.y);
      }
      xpart_s[p * 256 + h] = xa;
    }
    __syncthreads();  // B1: partials + gates_s visible
    if (tid < 256) {
      x1_s[xsw(h)] = xpart_s[h] + xpart_s[256 + h] + xpart_s[512 + h]
                   + xpart_s[768 + h] + bWd_r;
    }
    __syncthreads();  // B2: x1_s ready

    // ===== Phase B: scores (16 lanes/query), softmax, context, y_til =====
    {
      const int tq = tid >> 4, lq = tid & 15;
      const unsigned short* y1r = Y1 + ((size_t)b * Tx + tq) * Mx + lq * 16;
      const int base = lq * XS;
      uint4 q0 = *(const uint4*)(y1r);
      uint4 q1 = *(const uint4*)(y1r + 8);
      float ps = 0.0f;
      {
        unsigned qq[8] = {q0.x, q0.y, q0.z, q0.w, q1.x, q1.y, q1.z, q1.w};
        #pragma unroll
        for (int j = 0; j < 8; ++j) {
          float2 x2 = *(const float2*)&x1_s[base + 2 * j];
          float2 v2 = *(const float2*)&vd_s[base + 2 * j];
          ps += tanh_fast(x2.x + bfl(qq[j])) * v2.x
              + tanh_fast(x2.y + bfh(qq[j])) * v2.y;
        }
      }
      ps += __shfl_xor(ps, 1, 64);
      ps += __shfl_xor(ps, 2, 64);
      ps += __shfl_xor(ps, 4, 64);
      ps += __shfl_xor(ps, 8, 64);
      if (lq == 0) l_s[tq] = ps;
    }
    __syncthreads();  // B3
    if (tid < 64) {   // softmax over T in wave 0
      float v = l_s[tid];
      float mx = v;
      #pragma unroll
      for (int o = 1; o < 64; o <<= 1) mx = fmaxf(mx, __shfl_xor(mx, o, 64));
      float e = __expf(v - mx);
      float sm = e;
      #pragma unroll
      for (int o = 1; o < 64; o <<= 1) sm += __shfl_xor(sm, o, 64);
      beta_s[tid] = e / sm;
    }
    __syncthreads();  // B4: beta ready
    // context: m = tid>>2, q = tid&3 over tt in [16q, 16q+16); in-wave reduce
    float cm;
    {
      const int m = tid >> 2, q = tid & 3;
      const unsigned short* er = encT_s + m * ETS + q * 16;
      float acc = 0.0f;
      #pragma unroll
      for (int j = 0; j < 8; ++j) {
        unsigned e2 = *(const unsigned*)(er + 2 * j);   // 2 bf16, 4B aligned
        float2 b2 = *(const float2*)&beta_s[q * 16 + 2 * j];
        acc += b2.x * bfl(e2) + b2.y * bfh(e2);
      }
      acc += __shfl_xor(acc, 1, 64);
      acc += __shfl_xor(acc, 2, 64);
      cm = acc;                       // valid where q==0
      if (q == 0) c_s[m] = cm;
    }
    // y_til: sum_m c[m]*w_tilda[m] via full-wg reduction
    {
      float pt = ((tid & 3) == 0) ? cm * wtm : 0.0f;
      pt = wave_sum(pt);
      if ((tid & 63) == 0) red_s[tid >> 6] = pt;
    }
    __syncthreads();  // B5
    if (tid == 0) {
      float yt = 0.0f;
      #pragma unroll
      for (int i = 0; i < 16; ++i) yt += red_s[i];
      ytil_s = yt + wty * yv[b * Tx + t] + bwt;
    }
    __syncthreads();  // B6
    // ===== Phase C: LSTM cell (tid < 256) =====
    if (tid < 256) {
      const float ytil = ytil_s;
      float fi = sigm(gates_s[h]       + ytil * wih0);
      float ff = sigm(gates_s[256 + h] + ytil * wih1);
      float fg = tanh_fast(gates_s[512 + h] + ytil * wih2);
      float fo = sigm(gates_s[768 + h] + ytil * wih3);
      float spn = ff * sp_reg + fi * fg;
      float dn  = fo * tanh_fast(spn);
      sp_reg = spn;
      dsp_s[h] = dn;
      dsp_s[Hx + h] = (t == Tx - 1) ? c_s[h] : spn;  // final step: [d|c]
    }
    __syncthreads();  // B7: state ready for next step
  }

  // ===== Epilogue: out[b] = v_y . (W_y @ [d|c] + b_Wy) + b_vy =====
  {
    float a = 0.0f;
    const float* wy = Wyt + h;
    for (int k = 128 * p; k < 128 * p + 128; ++k)
      a += wy[(size_t)k * 256] * dsp_s[k];            // coalesced + broadcast
    xpart_s[p * 256 + h] = a;
  }
  __syncthreads();
  if (tid < 256) {
    float aa = xpart_s[h] + xpart_s[256 + h] + xpart_s[512 + h] + xpart_s[768 + h]
             + b_Wy[h];
    float po = aa * v_y[h];
    po = wave_sum(po);
    if ((tid & 63) == 0) red_s[tid >> 6] = po;
  }
  __syncthreads();
  if (tid == 0) out[b] = red_s[0] + red_s[1] + red_s[2] + red_s[3] + b_vy[0];
}

extern "C" void kernel_launch(void* const* d_in, const int* in_sizes, int n_in,
                              void* d_out, int out_size, void* d_ws, size_t ws_size,
                              hipStream_t stream) {
  const float* enc     = (const float*)d_in[0];
  const float* yv      = (const float*)d_in[1];
  const float* W_d     = (const float*)d_in[2];
  const float* b_Wd    = (const float*)d_in[3];
  const float* U_d     = (const float*)d_in[4];
  const float* v_d     = (const float*)d_in[5];
  const float* w_tilda = (const float*)d_in[6];
  const float* b_wt    = (const float*)d_in[7];
  const float* W_ih    = (const float*)d_in[8];
  const float* W_hh    = (const float*)d_in[9];
  const float* b_ih    = (const float*)d_in[10];
  const float* b_hh    = (const float*)d_in[11];
  const float* W_y     = (const float*)d_in[12];
  const float* b_Wy    = (const float*)d_in[13];
  const float* v_y     = (const float*)d_in[14];
  const float* b_vy    = (const float*)d_in[15];
  float* outp = (float*)d_out;

  char* ws = (char*)d_ws;
  uint2* Wd4  = (uint2*)ws;                               // 256 KB
  uint2* Whh4 = (uint2*)(ws + (256 << 10));               // 512 KB
  uint2* Ud4  = (uint2*)(ws + (768 << 10));               // 128 KB
  float* Wyt  = (float*)(ws + (896 << 10));               // 512 KB
  unsigned short* Y1 = (unsigned short*)(ws + (1408 << 10));  // 8 MB

  hipLaunchKernelGGL(pack_weights, dim3(384), dim3(256), 0, stream,
                     W_d, W_hh, U_d, W_y, Wd4, Whh4, Ud4, Wyt);
  hipLaunchKernelGGL(fused, dim3(Bx), dim3(NT), 0, stream,
                     enc, yv, b_Wd, v_d, w_tilda, b_wt, W_ih, b_ih, b_hh,
                     b_Wy, v_y, b_vy, Wd4, Whh4, Ud4, Wyt, Y1, outp);
}

// Round 4
// 878.235 us; speedup vs baseline: 7.6533x; 1.3855x over previous
//
#include <hip/hip_runtime.h>

// ---------------------------------------------------------------------------
// TemporalAttnLayer: B=256, T=64, M=256, H=256
//
// Round-4: round-3 structure (256 independent 1024-thread wgs, weights
// streamed from L2) with the per-MAC instruction count slashed:
//  - fp16 everywhere (weights, d/sp, enc, Y1): more precise than bf16 here
//  - v_dot2_f32_f16 (__builtin_amdgcn_fdot2): 1 VALU op / 2 MACs, no unpack
//  - k8-major uint4 weight packing: 16B loads, half the addressing
//  - d/sp as packed f16 in LDS: half the ds_read traffic, dot2-ready
//  - stage-1 (Y1 = enc@U_d^T) via v_pk_fma_f32 packed fp32 (2 MAC/instr)
//  - 6 barriers/step (was 7)
// ---------------------------------------------------------------------------

#define Bx 256
#define Tx 64
#define Mx 256
#define Hx 256
#define NT 1024
#define ETS 66    // encT_s row stride in ushorts
#define XS 18     // swizzled chunk stride for x1/v_d

typedef unsigned int  uint;
typedef unsigned short ushort;
typedef _Float16 h2  __attribute__((ext_vector_type(2)));
typedef float    f2v __attribute__((ext_vector_type(2)));

__device__ __forceinline__ float4 ld4(const float* p) { return *(const float4*)p; }
__device__ __forceinline__ float h2f(ushort s) {
  union { ushort s; _Float16 h; } c; c.s = s; return (float)c.h;
}
__device__ __forceinline__ ushort f2h(float f) {
  union { _Float16 h; ushort s; } c; c.h = (_Float16)f; return c.s;  // RNE
}
__device__ __forceinline__ uint pk2(float a, float b) {
  return (uint)f2h(a) | ((uint)f2h(b) << 16);
}
__device__ __forceinline__ float tanh_fast(float x) {
  float e2 = __expf(2.0f * x);
  return 1.0f - 2.0f / (e2 + 1.0f);
}
__device__ __forceinline__ float sigm(float x) {
  return 1.0f / (1.0f + __expf(-x));
}
__device__ __forceinline__ float wave_sum(float v) {
  #pragma unroll
  for (int o = 1; o < 64; o <<= 1) v += __shfl_xor(v, o, 64);
  return v;
}
__device__ __forceinline__ int xsw(int m) { return (m >> 4) * XS + (m & 15); }

// dot2: acc += w(2xf16) . a(2xf16)
#if defined(__has_builtin)
#if __has_builtin(__builtin_amdgcn_fdot2)
#define HAVE_FDOT2 1
#endif
#endif
__device__ __forceinline__ float dot2u(uint w, uint a, float acc) {
#ifdef HAVE_FDOT2
  h2 W = __builtin_bit_cast(h2, w);
  h2 A = __builtin_bit_cast(h2, a);
  return __builtin_amdgcn_fdot2(W, A, acc, false);
#else
  return acc + h2f((ushort)w) * h2f((ushort)a)
             + h2f((ushort)(w >> 16)) * h2f((ushort)(a >> 16));
#endif
}
// acc += all 8 f16 products from two uint4s
__device__ __forceinline__ float dot8(uint4 w, uint4 a, float acc) {
  acc = dot2u(w.x, a.x, acc);
  acc = dot2u(w.y, a.y, acc);
  acc = dot2u(w.z, a.z, acc);
  acc = dot2u(w.w, a.w, acc);
  return acc;
}

// ---------------------------------------------------------------------------
// Pack kernel: fp32 weights -> f16 k8-major uint4; W_y -> fp32 transposed.
//   Whh8[k8][j]  k8<32, j<1024 : uint4 = f16(W_hh[j][8k8..+7])   (512 KB)
//   Wd8 [k8][n]  k8<64, n<256  : uint4 = f16(W_d[n][8k8..+7])    (256 KB)
//   Ud8 [m8][n]  m8<32, n<256  : uint4 = f16(U_d[n][8m8..+7])    (128 KB)
//   Wyt [k][h]   k<512         : float = W_y[h][k]               (512 KB)
// grid 256 x 256
// ---------------------------------------------------------------------------
__global__ __launch_bounds__(256)
void pack_weights(const float* __restrict__ W_d,
                  const float* __restrict__ W_hh,
                  const float* __restrict__ U_d,
                  const float* __restrict__ W_y,
                  uint4* __restrict__ Whh8,
                  uint4* __restrict__ Wd8,
                  uint4* __restrict__ Ud8,
                  float* __restrict__ Wyt) {
  const int blk = blockIdx.x, tid = threadIdx.x;
  if (blk < 32) {                        // Whh8
    const int k8 = blk;
    #pragma unroll
    for (int q = 0; q < 4; ++q) {
      const int j = tid + 256 * q;
      float4 a = ld4(W_hh + (size_t)j * 256 + 8 * k8);
      float4 b = ld4(W_hh + (size_t)j * 256 + 8 * k8 + 4);
      Whh8[k8 * 1024 + j] = uint4{pk2(a.x, a.y), pk2(a.z, a.w),
                                  pk2(b.x, b.y), pk2(b.z, b.w)};
    }
  } else if (blk < 96) {                 // Wd8
    const int k8 = blk - 32;
    float4 a = ld4(W_d + (size_t)tid * 512 + 8 * k8);
    float4 b = ld4(W_d + (size_t)tid * 512 + 8 * k8 + 4);
    Wd8[k8 * 256 + tid] = uint4{pk2(a.x, a.y), pk2(a.z, a.w),
                                pk2(b.x, b.y), pk2(b.z, b.w)};
  } else if (blk < 128) {                // Ud8
    const int m8 = blk - 96;
    float4 a = ld4(U_d + (size_t)tid * 256 + 8 * m8);
    float4 b = ld4(U_d + (size_t)tid * 256 + 8 * m8 + 4);
    Ud8[m8 * 256 + tid] = uint4{pk2(a.x, a.y), pk2(a.z, a.w),
                                pk2(b.x, b.y), pk2(b.z, b.w)};
  } else {                               // Wyt transpose
    const int k0 = (blk - 128) * 4;
    float4 w = ld4(W_y + (size_t)tid * 512 + k0);
    Wyt[(k0 + 0) * 256 + tid] = w.x;
    Wyt[(k0 + 1) * 256 + tid] = w.y;
    Wyt[(k0 + 2) * 256 + tid] = w.z;
    Wyt[(k0 + 3) * 256 + tid] = w.w;
  }
}

// ---------------------------------------------------------------------------
// Main kernel: one 1024-thread wg per batch element, fully independent.
// ---------------------------------------------------------------------------
__global__ __launch_bounds__(NT, 4)
void fused(const float* __restrict__ enc,      // (T,B,M)
           const float* __restrict__ yv,       // (B,T,1)
           const float* __restrict__ b_Wd,     // (M)
           const float* __restrict__ v_d,      // (1,M)
           const float* __restrict__ w_tilda,  // (1,M+1)
           const float* __restrict__ b_wt,     // (1)
           const float* __restrict__ W_ih,     // (4H,1)
           const float* __restrict__ b_ih,     // (4H)
           const float* __restrict__ b_hh,     // (4H)
           const float* __restrict__ b_Wy,     // (H)
           const float* __restrict__ v_y,      // (1,H)
           const float* __restrict__ b_vy,     // (1)
           const uint4* __restrict__ Whh8,
           const uint4* __restrict__ Wd8,
           const uint4* __restrict__ Ud8,
           const float* __restrict__ Wyt,
           ushort* __restrict__ Y1,            // (B,T,M) f16 scratch
           float* __restrict__ out)            // (B,1)
{
  __shared__ ushort encT_s[Mx * ETS];                 // 33.8 KB [m][t] f16
  __shared__ __align__(16) ushort dsp2_s[2 * Hx];     // [d|sp] f16-packed, 1 KB
  __shared__ float dcfin_s[2 * Hx];                   // [d|c] fp32 (epilogue)
  __shared__ float x1_s[16 * XS];
  __shared__ float vd_s[16 * XS];
  __shared__ float xpart_s[4 * 256];
  __shared__ float gates_s[1024];
  __shared__ float c_s[256];
  __shared__ float l_s[Tx];
  __shared__ float beta_s[Tx];
  __shared__ float red_s[16];

  const int b   = blockIdx.x;
  const int tid = threadIdx.x;     // 0..1023
  const int h   = tid & 255;
  const int p   = tid >> 8;        // 0..3
  const size_t BM = (size_t)Bx * Mx;

  // ---- stage 0: enc[b] -> LDS transposed f16; init state; cache v_d ----
  for (int i = tid; i < Tx * Mx; i += NT) {
    int t = i >> 8, m = i & 255;
    encT_s[m * ETS + t] = f2h(enc[(size_t)t * BM + (size_t)b * Mx + m]);
  }
  if (tid < 512) dsp2_s[tid] = 0;
  if (tid < 256) vd_s[xsw(tid)] = v_d[tid];

  // ---- per-thread cached parameters ----
  const float bj  = b_ih[tid] + b_hh[tid];     // bias of gate j = tid
  const float wtm = w_tilda[tid >> 2];
  float bWd_r = 0.f, wih0 = 0.f, wih1 = 0.f, wih2 = 0.f, wih3 = 0.f;
  if (tid < 256) {
    bWd_r = b_Wd[h];
    wih0 = W_ih[h]; wih1 = W_ih[h + 256]; wih2 = W_ih[h + 512]; wih3 = W_ih[h + 768];
  }
  const float wty = w_tilda[Mx];
  const float bwt = b_wt[0];

  // ---- stage 1: Y1[b] = enc[b] @ U_d^T  (packed-fp32 FMA, f16 weights) ----
  {
    const int n = h;
    const float* eb = enc + (size_t)b * Mx;
    for (int tb = p * 16; tb < p * 16 + 16; tb += 8) {
      f2v acc2[8];
      #pragma unroll
      for (int j = 0; j < 8; ++j) acc2[j] = f2v{0.f, 0.f};
      #pragma unroll 2
      for (int m8 = 0; m8 < 32; ++m8) {
        uint4 u = Ud8[m8 * 256 + n];
        f2v w01 = f2v{h2f((ushort)u.x), h2f((ushort)(u.x >> 16))};
        f2v w23 = f2v{h2f((ushort)u.y), h2f((ushort)(u.y >> 16))};
        f2v w45 = f2v{h2f((ushort)u.z), h2f((ushort)(u.z >> 16))};
        f2v w67 = f2v{h2f((ushort)u.w), h2f((ushort)(u.w >> 16))};
        #pragma unroll
        for (int j = 0; j < 8; ++j) {
          const float* ep = eb + (size_t)(tb + j) * BM + 8 * m8;  // uniform
          float4 ea = ld4(ep), eb4 = ld4(ep + 4);
          acc2[j] += f2v{ea.x, ea.y} * w01;
          acc2[j] += f2v{ea.z, ea.w} * w23;
          acc2[j] += f2v{eb4.x, eb4.y} * w45;
          acc2[j] += f2v{eb4.z, eb4.w} * w67;
        }
      }
      #pragma unroll
      for (int j = 0; j < 8; ++j)
        Y1[((size_t)b * Tx + tb + j) * Mx + n] = f2h(acc2[j].x + acc2[j].y);
    }
  }
  __syncthreads();  // encT_s, dsp2_s, vd_s ready

  float sp_reg = 0.0f;   // thread h's sp (tid < 256)

  for (int t = 0; t < Tx; ++t) {
    // ===== Phase A: gates (output-split) + x1 (K-split), f16 dot2 =====
    {
      const uint4* dq = (const uint4*)dsp2_s;   // 64 x uint4 = [d|sp] f16
      // gate j = tid over K=256 (d half)
      float g = bj;
      const uint4* wp = Whh8 + tid;
      #pragma unroll 8
      for (int k8 = 0; k8 < 32; ++k8)
        g = dot8(wp[k8 * 1024], dq[k8], g);
      gates_s[tid] = g;
      // x1[h] partial over K-range [128p, 128p+128) of [d|sp]
      float xa = 0.0f;
      const uint4* xp = Wd8 + h;
      #pragma unroll 8
      for (int i = 0; i < 16; ++i) {
        const int k8 = p * 16 + i;
        xa = dot8(xp[k8 * 256], dq[k8], xa);
      }
      xpart_s[p * 256 + h] = xa;
    }
    __syncthreads();  // B1
    if (tid < 256) {
      x1_s[xsw(h)] = xpart_s[h] + xpart_s[256 + h] + xpart_s[512 + h]
                   + xpart_s[768 + h] + bWd_r;
    }
    __syncthreads();  // B2

    // ===== Phase B: scores (16 lanes/query) =====
    {
      const int tq = tid >> 4, lq = tid & 15;
      const ushort* y1r = Y1 + ((size_t)b * Tx + tq) * Mx + lq * 16;
      const int base = lq * XS;
      uint4 q0 = *(const uint4*)(y1r);
      uint4 q1 = *(const uint4*)(y1r + 8);
      float ps = 0.0f;
      {
        uint qq[8] = {q0.x, q0.y, q0.z, q0.w, q1.x, q1.y, q1.z, q1.w};
        #pragma unroll
        for (int j = 0; j < 8; ++j) {
          float2 x2 = *(const float2*)&x1_s[base + 2 * j];
          float2 v2 = *(const float2*)&vd_s[base + 2 * j];
          ps += tanh_fast(x2.x + h2f((ushort)qq[j])) * v2.x
              + tanh_fast(x2.y + h2f((ushort)(qq[j] >> 16))) * v2.y;
        }
      }
      ps += __shfl_xor(ps, 1, 64);
      ps += __shfl_xor(ps, 2, 64);
      ps += __shfl_xor(ps, 4, 64);
      ps += __shfl_xor(ps, 8, 64);
      if (lq == 0) l_s[tq] = ps;
    }
    __syncthreads();  // B3
    if (tid < 64) {   // softmax over T in wave 0
      float v = l_s[tid];
      float mx = v;
      #pragma unroll
      for (int o = 1; o < 64; o <<= 1) mx = fmaxf(mx, __shfl_xor(mx, o, 64));
      float e = __expf(v - mx);
      float sm = e;
      #pragma unroll
      for (int o = 1; o < 64; o <<= 1) sm += __shfl_xor(sm, o, 64);
      beta_s[tid] = e / sm;
    }
    __syncthreads();  // B4
    // context: m = tid>>2, q = tid&3 over tt in [16q,16q+16)
    float cm;
    {
      const int m = tid >> 2, q = tid & 3;
      const ushort* er = encT_s + m * ETS + q * 16;
      float acc = 0.0f;
      #pragma unroll
      for (int j = 0; j < 8; ++j) {
        uint e2 = *(const uint*)(er + 2 * j);
        float2 b2 = *(const float2*)&beta_s[q * 16 + 2 * j];
        acc += b2.x * h2f((ushort)e2) + b2.y * h2f((ushort)(e2 >> 16));
      }
      acc += __shfl_xor(acc, 1, 64);
      acc += __shfl_xor(acc, 2, 64);
      cm = acc;                       // valid where q==0
      if (q == 0) c_s[m] = cm;
    }
    // y_til partial reduction
    {
      float pt = ((tid & 3) == 0) ? cm * wtm : 0.0f;
      pt = wave_sum(pt);
      if ((tid & 63) == 0) red_s[tid >> 6] = pt;
    }
    __syncthreads();  // B5: red_s + c_s + gates_s all visible
    // ===== Phase C: LSTM cell (tid < 256); ytil computed locally =====
    if (tid < 256) {
      float4 r0 = *(const float4*)&red_s[0];
      float4 r1 = *(const float4*)&red_s[4];
      float4 r2 = *(const float4*)&red_s[8];
      float4 r3 = *(const float4*)&red_s[12];
      float ytil = r0.x + r0.y + r0.z + r0.w + r1.x + r1.y + r1.z + r1.w
                 + r2.x + r2.y + r2.z + r2.w + r3.x + r3.y + r3.z + r3.w
                 + wty * yv[b * Tx + t] + bwt;
      float fi = sigm(gates_s[h]       + ytil * wih0);
      float ff = sigm(gates_s[256 + h] + ytil * wih1);
      float fg = tanh_fast(gates_s[512 + h] + ytil * wih2);
      float fo = sigm(gates_s[768 + h] + ytil * wih3);
      float spn = ff * sp_reg + fi * fg;
      float dn  = fo * tanh_fast(spn);
      sp_reg = spn;
      dsp2_s[h]       = f2h(dn);
      dsp2_s[256 + h] = f2h(spn);
      if (t == Tx - 1) { dcfin_s[h] = dn; dcfin_s[256 + h] = c_s[h]; }
    }
    __syncthreads();  // B6: state ready for next step
  }

  // ===== Epilogue: out[b] = v_y . (W_y @ [d|c] + b_Wy) + b_vy =====
  {
    float a = 0.0f;
    const float* wy = Wyt + h;
    for (int k = 128 * p; k < 128 * p + 128; ++k)
      a += wy[(size_t)k * 256] * dcfin_s[k];
    xpart_s[p * 256 + h] = a;
  }
  __syncthreads();
  if (tid < 256) {
    float aa = xpart_s[h] + xpart_s[256 + h] + xpart_s[512 + h] + xpart_s[768 + h]
             + b_Wy[h];
    float po = aa * v_y[h];
    po = wave_sum(po);
    if ((tid & 63) == 0) red_s[tid >> 6] = po;
  }
  __syncthreads();
  if (tid == 0) out[b] = red_s[0] + red_s[1] + red_s[2] + red_s[3] + b_vy[0];
}

extern "C" void kernel_launch(void* const* d_in, const int* in_sizes, int n_in,
                              void* d_out, int out_size, void* d_ws, size_t ws_size,
                              hipStream_t stream) {
  const float* enc     = (const float*)d_in[0];
  const float* yv      = (const float*)d_in[1];
  const float* W_d     = (const float*)d_in[2];
  const float* b_Wd    = (const float*)d_in[3];
  const float* U_d     = (const float*)d_in[4];
  const float* v_d     = (const float*)d_in[5];
  const float* w_tilda = (const float*)d_in[6];
  const float* b_wt    = (const float*)d_in[7];
  const float* W_ih    = (const float*)d_in[8];
  const float* W_hh    = (const float*)d_in[9];
  const float* b_ih    = (const float*)d_in[10];
  const float* b_hh    = (const float*)d_in[11];
  const float* W_y     = (const float*)d_in[12];
  const float* b_Wy    = (const float*)d_in[13];
  const float* v_y     = (const float*)d_in[14];
  const float* b_vy    = (const float*)d_in[15];
  float* outp = (float*)d_out;

  char* ws = (char*)d_ws;
  uint4* Whh8 = (uint4*)ws;                                // 512 KB
  uint4* Wd8  = (uint4*)(ws + (512 << 10));                // 256 KB
  uint4* Ud8  = (uint4*)(ws + (768 << 10));                // 128 KB
  float* Wyt  = (float*)(ws + (896 << 10));                // 512 KB
  ushort* Y1  = (ushort*)(ws + (1408 << 10));              // 8 MB

  hipLaunchKernelGGL(pack_weights, dim3(256), dim3(256), 0, stream,
                     W_d, W_hh, U_d, W_y, Whh8, Wd8, Ud8, Wyt);
  hipLaunchKernelGGL(fused, dim3(Bx), dim3(NT), 0, stream,
                     enc, yv, b_Wd, v_d, w_tilda, b_wt, W_ih, b_ih, b_hh,
                     b_Wy, v_y, b_vy, Whh8, Wd8, Ud8, Wyt, Y1, outp);
}